// Round 14
// baseline (20.065 us; speedup 1.0000x reference)
//
#include <hip/hip_runtime.h>

#define BATCH   65536
#define NREL    100
#define NBB     64            // counting-sort blocks; each owns 1024 batch elements
#define NGB     512           // d-gather blocks; each thread does 2 row-quarters
#define NTILE   16            // 16 x 64-row tiles per relation

typedef __attribute__((ext_vector_type(8))) short bf16x8;
typedef __attribute__((ext_vector_type(4))) float f32x4;

__device__ __forceinline__ unsigned short f2bf(float x) {   // RNE f32->bf16
    unsigned u = __float_as_uint(x);
    u += 0x7fffu + ((u >> 16) & 1u);
    return (unsigned short)(u >> 16);
}

// ---- Kernel A: prep = [0..63: counting sort] + [64..163: P->bf16 image]
//                     + [164..675: d-gather, 2 rows/thread] ----------------
__launch_bounds__(256)
__global__ void transr_prep(const int* __restrict__ relation,
                            const int* __restrict__ head,
                            const int* __restrict__ tail,
                            const float* __restrict__ proj,
                            const float* __restrict__ ent,
                            int* __restrict__ ws_hist,
                            int* __restrict__ ws_lpfx,
                            int* __restrict__ ws_bucket,
                            unsigned short* __restrict__ ws_pbf,
                            unsigned short* __restrict__ ws_dbuf) {
    const int tid = threadIdx.x, bid = blockIdx.x;

    if (bid < NBB) {
        // ---- counting sort (validated r7-r13)
        __shared__ int hist[NREL];
        __shared__ int scan[128];

        for (int r = tid; r < NREL; r += 256) hist[r] = 0;
        __syncthreads();

        const int4 v = ((const int4*)relation)[bid * 256 + tid];
        const int vals[4] = {v.x, v.y, v.z, v.w};
        int lr[4];
        #pragma unroll
        for (int k = 0; k < 4; ++k) lr[k] = atomicAdd(&hist[vals[k]], 1);
        __syncthreads();

        if (tid < 128) scan[tid] = (tid < NREL) ? hist[tid] : 0;
        __syncthreads();
        #pragma unroll
        for (int off = 1; off < 128; off <<= 1) {      // Hillis-Steele inclusive
            int t = 0;
            if (tid < 128 && tid >= off) t = scan[tid - off];
            __syncthreads();
            if (tid < 128) scan[tid] += t;
            __syncthreads();
        }

        const int i0 = (bid * 256 + tid) * 4;
        #pragma unroll
        for (int k = 0; k < 4; ++k) {
            const int rel = vals[k];
            ws_bucket[bid * 1024 + (scan[rel] - hist[rel]) + lr[k]] = i0 + k;
        }
        for (int r = tid; r < NREL; r += 256) {
            ws_hist[r * NBB + bid] = hist[r];
            ws_lpfx[r * NBB + bid] = scan[r] - hist[r];
        }
    } else if (bid < NBB + NREL) {
        // ---- P -> swizzled bf16 image (validated r8-r13)
        const int rel = bid - NBB;
        const int n = tid >> 2, q = tid & 3;
        const float* Pr = proj + (size_t)rel * 4096;
        unsigned short* dst = ws_pbf + (size_t)rel * 4096;
        #pragma unroll
        for (int kh = 0; kh < 2; ++kh) {
            const int khi = q * 2 + kh;
            unsigned short u[8];
            #pragma unroll
            for (int klo = 0; klo < 8; ++klo)
                u[klo] = f2bf(Pr[(khi * 8 + klo) * 64 + n]);
            *(bf16x8*)&dst[n * 64 + ((khi ^ (n & 7)) << 3)] = *(bf16x8*)u;
        }
    } else {
        // ---- d-gather: 2 independent row-quarters per thread (2x MLP)
        const int idx0 = (bid - NBB - NREL) * 256 + tid;
        #pragma unroll
        for (int half = 0; half < 2; ++half) {
            const int idx = idx0 + half * (NGB * 256);
            const int row = idx >> 2, q = idx & 3;
            const int h = head[row], t = tail[row];
            const float4* h4 = (const float4*)(ent + (size_t)h * 64) + q * 4;
            const float4* t4 = (const float4*)(ent + (size_t)t * 64) + q * 4;
            unsigned short u[16];
            #pragma unroll
            for (int m = 0; m < 4; ++m) {
                float4 a = h4[m], c = t4[m];
                u[m * 4 + 0] = f2bf(a.x - c.x);
                u[m * 4 + 1] = f2bf(a.y - c.y);
                u[m * 4 + 2] = f2bf(a.z - c.z);
                u[m * 4 + 3] = f2bf(a.w - c.w);
            }
            bf16x8* dst = (bf16x8*)&ws_dbuf[(size_t)row * 64 + q * 16];
            dst[0] = *(bf16x8*)&u[0];
            dst[1] = *(bf16x8*)&u[8];
        }
    }
}

// ---- Kernel B: MFMA per-(relation, 64-row tile) ---------------------------
// r14: B-fragments loaded DIRECTLY from the pre-swizzled global image into
// registers, issued before the A-chain (in flight during search->dbuf; MFMA
// waits on vmcnt, not the barrier). No Bbuf: barrier guards Abuf only.
// Value-bearing math identical to rounds 5-13 -> absmax stays exactly 128.
__launch_bounds__(256, 4)
__global__ void transr_compute(const float* __restrict__ remb,
                               const int* __restrict__ ws_hist,
                               const int* __restrict__ ws_lpfx,
                               const int* __restrict__ ws_bucket,
                               const unsigned short* __restrict__ ws_pbf,
                               const unsigned short* __restrict__ ws_dbuf,
                               float* __restrict__ out) {
    __shared__ unsigned short Abuf[64 * 64];   // D rows (bf16), XOR-swizzled slices
    __shared__ int bidx_s[64];

    const int tid   = threadIdx.x;
    const int wid   = tid >> 6;
    const int lane  = tid & 63;
    const int rel   = blockIdx.y;
    const int start = blockIdx.x << 6;

    // per-wave register scan of this relation's 64 per-srcblock counts
    const int hown = ws_hist[rel * NBB + lane];
    const int lpfx = ws_lpfx[rel * NBB + lane];
    int hinc = hown;
    #pragma unroll
    for (int m = 1; m < 64; m <<= 1) {
        int t = __shfl_up(hinc, m);
        if (lane >= m) hinc += t;
    }
    const int hexc = hinc - hown;              // exclusive prefix, lane-indexed
    const int cnt  = __shfl(hinc, 63);
    if (start >= cnt) return;                  // empty tail tile: uniform exit

    // B-fragments direct from pre-swizzled global image (L2-hot), issued early
    const unsigned short* Pimg = ws_pbf + (size_t)rel * 4096;
    const int g = lane >> 4;
    bf16x8 bv[2][4];
    #pragma unroll
    for (int s = 0; s < 2; ++s) {
        const int ks = g + s * 4;
        #pragma unroll
        for (int f = 0; f < 4; ++f) {
            const int col = f * 16 + (lane & 15);
            bv[s][f] = *(const bf16x8*)&Pimg[col * 64 + ((ks ^ (col & 7)) * 8)];
        }
    }

    // remb folded into acc init via direct L1-broadcast loads
    const float* Rr = remb + rel * 64;
    f32x4 acc[4];
    #pragma unroll
    for (int f = 0; f < 4; ++f) {
        const float rv = Rr[f * 16 + (lane & 15)];
        acc[f] = (f32x4){rv, rv, rv, rv};
    }

    // stage A: thread = (row = tid>>2, quarter q = tid&3); 32B bf16 copy
    {
        const int row = tid >> 2, q = tid & 3;
        const int j  = start + row;
        const int jj = (j < cnt) ? j : (cnt - 1);
        int lo = 0;                            // last c with hexc[c] <= jj
        #pragma unroll
        for (int s = 32; s; s >>= 1) {
            const int c = lo + s;
            const int v = __shfl(hexc, c & 63);
            if (c < 64 && v <= jj) lo = c;
        }
        const int b = ws_bucket[lo * 1024 + __shfl(lpfx, lo) + (jj - __shfl(hexc, lo))];
        if (q == 0) bidx_s[row] = b;
        const bf16x8* src = (const bf16x8*)&ws_dbuf[(size_t)b * 64 + q * 16];
        const bf16x8 u0 = src[0];
        const bf16x8 u1 = src[1];
        *(bf16x8*)&Abuf[row * 64 + (((q * 2)     ^ (row & 7)) * 8)] = u0;
        *(bf16x8*)&Abuf[row * 64 + (((q * 2 + 1) ^ (row & 7)) * 8)] = u1;
    }
    __syncthreads();                           // guards Abuf only

    // MFMA: wave strip = rows wid*16..+15; 2 k-steps x 4 n-tiles
    const int arow = wid * 16 + (lane & 15);
    #pragma unroll
    for (int s = 0; s < 2; ++s) {
        const int ks = g + s * 4;
        bf16x8 av = *(const bf16x8*)&Abuf[arow * 64 + ((ks ^ (arow & 7)) * 8)];
        #pragma unroll
        for (int f = 0; f < 4; ++f)
            acc[f] = __builtin_amdgcn_mfma_f32_16x16x32_bf16(av, bv[s][f], acc[f], 0, 0, 0);
    }

    // epilogue: score = sum of squares; reduce across 16 col-lanes
    float ps[4];
    #pragma unroll
    for (int r = 0; r < 4; ++r)
        ps[r] = acc[0][r] * acc[0][r] + acc[1][r] * acc[1][r] +
                acc[2][r] * acc[2][r] + acc[3][r] * acc[3][r];
    #pragma unroll
    for (int m = 1; m < 16; m <<= 1) {
        #pragma unroll
        for (int r = 0; r < 4; ++r) ps[r] += __shfl_xor(ps[r], m, 64);
    }
    if ((lane & 15) == 0) {
        const int rowb = wid * 16 + g * 4;
        #pragma unroll
        for (int r = 0; r < 4; ++r) {
            const int j = start + rowb + r;
            if (j < cnt) out[bidx_s[rowb + r]] = ps[r];
        }
    }
}

extern "C" void kernel_launch(void* const* d_in, const int* in_sizes, int n_in,
                              void* d_out, int out_size, void* d_ws, size_t ws_size,
                              hipStream_t stream) {
    const int*   head     = (const int*)d_in[0];
    const int*   relation = (const int*)d_in[1];
    const int*   tail     = (const int*)d_in[2];
    const float* ent      = (const float*)d_in[3];
    const float* remb     = (const float*)d_in[4];
    const float* proj     = (const float*)d_in[5];
    float*       out      = (float*)d_out;

    // ws layout (every read cell rewritten each call -> no zeroing needed):
    int* ws_hist = (int*)d_ws;                              // [100*64] @ 0
    int* ws_lpfx = (int*)d_ws + 8192;                       // [100*64] @ 32 KB
    int* ws_bucket = (int*)((char*)d_ws + 65536);           // [64*1024] @ 64 KB (256 KB)
    unsigned short* ws_pbf =
        (unsigned short*)((char*)d_ws + 512 * 1024);        // [100*4096] @ 512 KB (800 KB)
    unsigned short* ws_dbuf =
        (unsigned short*)((char*)d_ws + 2 * 1024 * 1024);   // [65536*64] @ 2 MB (8.4 MB)

    transr_prep<<<NBB + NREL + NGB, 256, 0, stream>>>(
        relation, head, tail, proj, ent,
        ws_hist, ws_lpfx, ws_bucket, ws_pbf, ws_dbuf);
    transr_compute<<<dim3(NTILE, NREL), 256, 0, stream>>>(
        remb, ws_hist, ws_lpfx, ws_bucket, ws_pbf, ws_dbuf, out);
}

// Round 15
// 19.282 us; speedup vs baseline: 1.0406x; 1.0406x over previous
//
#include <hip/hip_runtime.h>

#define BATCH   65536
#define NREL    100
#define NBB     64            // counting-sort blocks; each owns 1024 batch elements
#define NGB     1024          // d-gather blocks; each owns 256 row-quarters
#define NTILE   16            // 16 x 64-row tiles per relation

typedef __attribute__((ext_vector_type(8))) short bf16x8;
typedef __attribute__((ext_vector_type(4))) float f32x4;

__device__ __forceinline__ unsigned short f2bf(float x) {   // RNE f32->bf16
    unsigned u = __float_as_uint(x);
    u += 0x7fffu + ((u >> 16) & 1u);
    return (unsigned short)(u >> 16);
}

// ---- Kernel A: prep = [0..63: counting sort] + [64..163: P->bf16 image]
//                     + [164..1187: d-gather] ------------------------------
// d-gather: dbuf[i] = bf16(ent[head[i]] - ent[tail[i]]), natural order, no
// dependent chain (the random ent reads happen HERE with max parallelism);
// compute then reads 128B bf16 rows that are L3-resident (just written).
// All ws cells rewritten every call -> no zeroing, no memset node.
__launch_bounds__(256)
__global__ void transr_prep(const int* __restrict__ relation,
                            const int* __restrict__ head,
                            const int* __restrict__ tail,
                            const float* __restrict__ proj,
                            const float* __restrict__ ent,
                            int* __restrict__ ws_hist,
                            int* __restrict__ ws_lpfx,
                            int* __restrict__ ws_bucket,
                            unsigned short* __restrict__ ws_pbf,
                            unsigned short* __restrict__ ws_dbuf) {
    const int tid = threadIdx.x, bid = blockIdx.x;

    if (bid < NBB) {
        // ---- counting sort (validated r7-r13); bucket stores b only (int)
        __shared__ int hist[NREL];
        __shared__ int scan[128];

        for (int r = tid; r < NREL; r += 256) hist[r] = 0;
        __syncthreads();

        const int4 v = ((const int4*)relation)[bid * 256 + tid];
        const int vals[4] = {v.x, v.y, v.z, v.w};
        int lr[4];
        #pragma unroll
        for (int k = 0; k < 4; ++k) lr[k] = atomicAdd(&hist[vals[k]], 1);
        __syncthreads();

        if (tid < 128) scan[tid] = (tid < NREL) ? hist[tid] : 0;
        __syncthreads();
        #pragma unroll
        for (int off = 1; off < 128; off <<= 1) {      // Hillis-Steele inclusive
            int t = 0;
            if (tid < 128 && tid >= off) t = scan[tid - off];
            __syncthreads();
            if (tid < 128) scan[tid] += t;
            __syncthreads();
        }

        const int i0 = (bid * 256 + tid) * 4;
        #pragma unroll
        for (int k = 0; k < 4; ++k) {
            const int rel = vals[k];
            ws_bucket[bid * 1024 + (scan[rel] - hist[rel]) + lr[k]] = i0 + k;
        }
        for (int r = tid; r < NREL; r += 256) {
            ws_hist[r * NBB + bid] = hist[r];
            ws_lpfx[r * NBB + bid] = scan[r] - hist[r];
        }
    } else if (bid < NBB + NREL) {
        // ---- P -> swizzled bf16 image (validated r8-r13)
        const int rel = bid - NBB;
        const int n = tid >> 2, q = tid & 3;
        const float* Pr = proj + (size_t)rel * 4096;
        unsigned short* dst = ws_pbf + (size_t)rel * 4096;
        #pragma unroll
        for (int kh = 0; kh < 2; ++kh) {
            const int khi = q * 2 + kh;
            unsigned short u[8];
            #pragma unroll
            for (int klo = 0; klo < 8; ++klo)
                u[klo] = f2bf(Pr[(khi * 8 + klo) * 64 + n]);
            *(bf16x8*)&dst[n * 64 + ((khi ^ (n & 7)) << 3)] = *(bf16x8*)u;
        }
    } else {
        // ---- d-gather: thread = (row = idx>>2, quarter q = idx&3)
        const int idx = (bid - NBB - NREL) * 256 + tid;
        const int row = idx >> 2, q = idx & 3;
        const int h = head[row], t = tail[row];
        const float4* h4 = (const float4*)(ent + (size_t)h * 64) + q * 4;
        const float4* t4 = (const float4*)(ent + (size_t)t * 64) + q * 4;
        unsigned short u[16];
        #pragma unroll
        for (int m = 0; m < 4; ++m) {
            float4 a = h4[m], c = t4[m];
            u[m * 4 + 0] = f2bf(a.x - c.x);
            u[m * 4 + 1] = f2bf(a.y - c.y);
            u[m * 4 + 2] = f2bf(a.z - c.z);
            u[m * 4 + 3] = f2bf(a.w - c.w);
        }
        bf16x8* dst = (bf16x8*)&ws_dbuf[(size_t)row * 64 + q * 16];
        dst[0] = *(bf16x8*)&u[0];
        dst[1] = *(bf16x8*)&u[8];
    }
}

// ---- Kernel B: MFMA per-(relation, 64-row tile) ---------------------------
// A-stage: search -> 4B bucket -> 32B bf16 copy from L3-resident dbuf.
// B-stage: coalesced 8KB copy of the pre-swizzled image into LDS.
// Value-bearing math identical to rounds 5-13 -> absmax stays exactly 128.
__launch_bounds__(256, 4)
__global__ void transr_compute(const float* __restrict__ remb,
                               const int* __restrict__ ws_hist,
                               const int* __restrict__ ws_lpfx,
                               const int* __restrict__ ws_bucket,
                               const unsigned short* __restrict__ ws_pbf,
                               const unsigned short* __restrict__ ws_dbuf,
                               float* __restrict__ out) {
    __shared__ unsigned short Abuf[64 * 64];   // D rows (bf16), XOR-swizzled slices
    __shared__ unsigned short Bbuf[64 * 64];   // P^T  (bf16), pre-swizzled image
    __shared__ int bidx_s[64];

    const int tid   = threadIdx.x;
    const int wid   = tid >> 6;
    const int lane  = tid & 63;
    const int rel   = blockIdx.y;
    const int start = blockIdx.x << 6;

    // per-wave register scan of this relation's 64 per-srcblock counts
    const int hown = ws_hist[rel * NBB + lane];
    const int lpfx = ws_lpfx[rel * NBB + lane];
    int hinc = hown;
    #pragma unroll
    for (int m = 1; m < 64; m <<= 1) {
        int t = __shfl_up(hinc, m);
        if (lane >= m) hinc += t;
    }
    const int hexc = hinc - hown;              // exclusive prefix, lane-indexed
    const int cnt  = __shfl(hinc, 63);
    if (start >= cnt) return;                  // empty tail tile: uniform exit

    // independent B-image load issues early
    const uint4* bsrc = (const uint4*)(ws_pbf + (size_t)rel * 4096) + tid * 2;
    const uint4 bimg0 = bsrc[0];
    const uint4 bimg1 = bsrc[1];

    // remb folded into acc init via direct L1-broadcast loads
    const float* Rr = remb + rel * 64;
    f32x4 acc[4];
    #pragma unroll
    for (int f = 0; f < 4; ++f) {
        const float rv = Rr[f * 16 + (lane & 15)];
        acc[f] = (f32x4){rv, rv, rv, rv};
    }

    // stage A: thread = (row = tid>>2, quarter q = tid&3); 32B bf16 copy
    {
        const int row = tid >> 2, q = tid & 3;
        const int j  = start + row;
        const int jj = (j < cnt) ? j : (cnt - 1);
        int lo = 0;                            // last c with hexc[c] <= jj
        #pragma unroll
        for (int s = 32; s; s >>= 1) {
            const int c = lo + s;
            const int v = __shfl(hexc, c & 63);
            if (c < 64 && v <= jj) lo = c;
        }
        const int b = ws_bucket[lo * 1024 + __shfl(lpfx, lo) + (jj - __shfl(hexc, lo))];
        if (q == 0) bidx_s[row] = b;
        const bf16x8* src = (const bf16x8*)&ws_dbuf[(size_t)b * 64 + q * 16];
        const bf16x8 u0 = src[0];
        const bf16x8 u1 = src[1];
        *(bf16x8*)&Abuf[row * 64 + (((q * 2)     ^ (row & 7)) * 8)] = u0;
        *(bf16x8*)&Abuf[row * 64 + (((q * 2 + 1) ^ (row & 7)) * 8)] = u1;
    }
    {
        uint4* dst = (uint4*)Bbuf + tid * 2;
        dst[0] = bimg0;
        dst[1] = bimg1;
    }
    __syncthreads();                           // the only barrier

    // MFMA: wave strip = rows wid*16..+15; 2 k-steps x 4 n-tiles
    const int arow = wid * 16 + (lane & 15);
    const int g    = lane >> 4;
    #pragma unroll
    for (int s = 0; s < 2; ++s) {
        const int ks = g + s * 4;
        bf16x8 av = *(const bf16x8*)&Abuf[arow * 64 + ((ks ^ (arow & 7)) * 8)];
        #pragma unroll
        for (int f = 0; f < 4; ++f) {
            const int col = f * 16 + (lane & 15);
            bf16x8 bv = *(const bf16x8*)&Bbuf[col * 64 + ((ks ^ (col & 7)) * 8)];
            acc[f] = __builtin_amdgcn_mfma_f32_16x16x32_bf16(av, bv, acc[f], 0, 0, 0);
        }
    }

    // epilogue: score = sum of squares; reduce across 16 col-lanes
    float ps[4];
    #pragma unroll
    for (int r = 0; r < 4; ++r)
        ps[r] = acc[0][r] * acc[0][r] + acc[1][r] * acc[1][r] +
                acc[2][r] * acc[2][r] + acc[3][r] * acc[3][r];
    #pragma unroll
    for (int m = 1; m < 16; m <<= 1) {
        #pragma unroll
        for (int r = 0; r < 4; ++r) ps[r] += __shfl_xor(ps[r], m, 64);
    }
    if ((lane & 15) == 0) {
        const int rowb = wid * 16 + g * 4;
        #pragma unroll
        for (int r = 0; r < 4; ++r) {
            const int j = start + rowb + r;
            if (j < cnt) out[bidx_s[rowb + r]] = ps[r];
        }
    }
}

extern "C" void kernel_launch(void* const* d_in, const int* in_sizes, int n_in,
                              void* d_out, int out_size, void* d_ws, size_t ws_size,
                              hipStream_t stream) {
    const int*   head     = (const int*)d_in[0];
    const int*   relation = (const int*)d_in[1];
    const int*   tail     = (const int*)d_in[2];
    const float* ent      = (const float*)d_in[3];
    const float* remb     = (const float*)d_in[4];
    const float* proj     = (const float*)d_in[5];
    float*       out      = (float*)d_out;

    // ws layout (every read cell rewritten each call -> no zeroing needed):
    int* ws_hist = (int*)d_ws;                              // [100*64] @ 0
    int* ws_lpfx = (int*)d_ws + 8192;                       // [100*64] @ 32 KB
    int* ws_bucket = (int*)((char*)d_ws + 65536);           // [64*1024] @ 64 KB (256 KB)
    unsigned short* ws_pbf =
        (unsigned short*)((char*)d_ws + 512 * 1024);        // [100*4096] @ 512 KB (800 KB)
    unsigned short* ws_dbuf =
        (unsigned short*)((char*)d_ws + 2 * 1024 * 1024);   // [65536*64] @ 2 MB (8.4 MB)

    transr_prep<<<NBB + NREL + NGB, 256, 0, stream>>>(
        relation, head, tail, proj, ent,
        ws_hist, ws_lpfx, ws_bucket, ws_pbf, ws_dbuf);
    transr_compute<<<dim3(NTILE, NREL), 256, 0, stream>>>(
        remb, ws_hist, ws_lpfx, ws_bucket, ws_pbf, ws_dbuf, out);
}